// Round 1
// baseline (715.090 us; speedup 1.0000x reference)
//
#include <hip/hip_runtime.h>
#include <hip/hip_bf16.h>

#define D 128
#define SCAN_B 256
#define SCAN_ITEMS 4
#define SCAN_TILE 1024
#define GM 64   // GEMM rows per block

// ---------------- degree histogram ----------------
__global__ void k_degrees(const int* __restrict__ src, const int* __restrict__ dst,
                          int* __restrict__ outcnt, int* __restrict__ indeg, int E) {
    int e = blockIdx.x * blockDim.x + threadIdx.x;
    if (e < E) {
        atomicAdd(&outcnt[src[e]], 1);
        atomicAdd(&indeg[dst[e]], 1);
    }
}

// ---------------- inv = 1/max(outdeg,1); zero cursor ----------------
__global__ void k_makeinv(const int* __restrict__ outcnt, float* __restrict__ inv,
                          int* __restrict__ cursor, int n) {
    int i = blockIdx.x * blockDim.x + threadIdx.x;
    if (i < n) {
        int d = outcnt[i];
        inv[i] = 1.0f / (float)(d > 1 ? d : 1);
        cursor[i] = 0;
    }
}

// ---------------- scan step 1: per-block exclusive scan ----------------
__global__ void k_scan1(const int* __restrict__ indeg, int* __restrict__ row_start,
                        int* __restrict__ bsums, int n) {
    __shared__ int sh[SCAN_B];
    int base = blockIdx.x * SCAN_TILE + threadIdx.x * SCAN_ITEMS;
    int v[SCAN_ITEMS];
    int s = 0;
#pragma unroll
    for (int i = 0; i < SCAN_ITEMS; i++) {
        int idx = base + i;
        v[i] = (idx < n) ? indeg[idx] : 0;
        s += v[i];
    }
    sh[threadIdx.x] = s;
    __syncthreads();
    for (int off = 1; off < SCAN_B; off <<= 1) {
        int t = (threadIdx.x >= off) ? sh[threadIdx.x - off] : 0;
        __syncthreads();
        sh[threadIdx.x] += t;
        __syncthreads();
    }
    int excl = sh[threadIdx.x] - s;
    if (threadIdx.x == SCAN_B - 1) bsums[blockIdx.x] = sh[SCAN_B - 1];
    int run = excl;
#pragma unroll
    for (int i = 0; i < SCAN_ITEMS; i++) {
        int idx = base + i;
        if (idx < n) row_start[idx] = run;
        run += v[i];
    }
}

// ---------------- scan step 2: serial exclusive scan of block sums ----------------
__global__ void k_scan2(int* __restrict__ bsums, int nb) {
    if (threadIdx.x == 0 && blockIdx.x == 0) {
        int run = 0;
        for (int i = 0; i < nb; i++) {
            int v = bsums[i];
            bsums[i] = run;
            run += v;
        }
    }
}

// ---------------- scan step 3: add block offsets ----------------
__global__ void k_scan3(int* __restrict__ row_start, const int* __restrict__ bsums, int n) {
    int base = blockIdx.x * SCAN_TILE + threadIdx.x * SCAN_ITEMS;
    int add = bsums[blockIdx.x];
#pragma unroll
    for (int i = 0; i < SCAN_ITEMS; i++) {
        int idx = base + i;
        if (idx < n) row_start[idx] += add;
    }
}

// ---------------- CSR fill (store src per slot) ----------------
__global__ void k_fill(const int* __restrict__ src, const int* __restrict__ dst,
                       const int* __restrict__ row_start, int* __restrict__ cursor,
                       int* __restrict__ esrc, int E) {
    int e = blockIdx.x * blockDim.x + threadIdx.x;
    if (e < E) {
        int d = dst[e];
        int p = atomicAdd(&cursor[d], 1);
        esrc[row_start[d] + p] = src[e];
    }
}

// ---------------- SpMM gather: agg[node] = sum_{e in CSR row} h[src]*inv[src] ----------------
__global__ __launch_bounds__(128) void k_spmm(const float* __restrict__ h, const float* __restrict__ inv,
                                              const int* __restrict__ row_start, const int* __restrict__ indeg,
                                              const int* __restrict__ esrc, float* __restrict__ agg, int n) {
    int node = blockIdx.x;
    if (node >= n) return;
    int t = threadIdx.x;  // 0..127 = feature index
    int s0 = row_start[node];
    int cnt = indeg[node];
    float acc = 0.0f;
    int e = 0;
    for (; e + 1 < cnt; e += 2) {
        int sA = esrc[s0 + e];
        int sB = esrc[s0 + e + 1];
        float a = h[(size_t)sA * D + t];
        float b = h[(size_t)sB * D + t];
        acc += a * inv[sA];
        acc += b * inv[sB];
    }
    if (e < cnt) {
        int sA = esrc[s0 + e];
        acc += h[(size_t)sA * D + t] * inv[sA];
    }
    agg[(size_t)node * D + t] = acc;
}

// ---------------- GEMM (A[n x 128] @ W[128 x 128]) + bias + PReLU ----------------
__global__ __launch_bounds__(256) void k_gemm_bias_prelu(
    const float* __restrict__ A, const float* __restrict__ W,
    const float* __restrict__ bias, const float* __restrict__ pa,
    float* __restrict__ out, int n) {
    __shared__ float As[GM][D];  // 32 KB
    int tid = threadIdx.x;
    int cg = tid & 31;   // column group: 4 cols each
    int rg = tid >> 5;   // row group: 8 rows each
    int rowbase = blockIdx.x * GM;

    // stage A tile: 64x128 floats = 2048 float4, 8 per thread
    const float4* A4 = (const float4*)(A + (size_t)rowbase * D);
    float4* As4 = (float4*)&As[0][0];
#pragma unroll
    for (int i = 0; i < 8; i++) {
        int idx = tid + i * 256;      // 0..2047
        int r = idx >> 5;             // row in tile
        if (rowbase + r < n)
            As4[idx] = A4[idx];
        else
            As4[idx] = make_float4(0.f, 0.f, 0.f, 0.f);
    }
    __syncthreads();

    float acc[8][4];
#pragma unroll
    for (int r = 0; r < 8; r++)
#pragma unroll
        for (int c = 0; c < 4; c++) acc[r][c] = 0.0f;

    const float* Wp = W + cg * 4;
#pragma unroll 4
    for (int k = 0; k < D; k++) {
        float4 w = *(const float4*)(Wp + (size_t)k * D);
#pragma unroll
        for (int r = 0; r < 8; r++) {
            float a = As[rg * 8 + r][k];
            acc[r][0] += a * w.x;
            acc[r][1] += a * w.y;
            acc[r][2] += a * w.z;
            acc[r][3] += a * w.w;
        }
    }

    float alpha = pa[0];
    float4 bb = *(const float4*)(bias + cg * 4);
#pragma unroll
    for (int r = 0; r < 8; r++) {
        int row = rowbase + rg * 8 + r;
        if (row < n) {
            float4 z;
            z.x = acc[r][0] + bb.x;
            z.y = acc[r][1] + bb.y;
            z.z = acc[r][2] + bb.z;
            z.w = acc[r][3] + bb.w;
            z.x = (z.x >= 0.f) ? z.x : alpha * z.x;
            z.y = (z.y >= 0.f) ? z.y : alpha * z.y;
            z.z = (z.z >= 0.f) ? z.z : alpha * z.z;
            z.w = (z.w >= 0.f) ? z.w : alpha * z.w;
            *(float4*)(out + (size_t)row * D + cg * 4) = z;
        }
    }
}

extern "C" void kernel_launch(void* const* d_in, const int* in_sizes, int n_in,
                              void* d_out, int out_size, void* d_ws, size_t ws_size,
                              hipStream_t stream) {
    const float* x   = (const float*)d_in[0];
    const int* src   = (const int*)d_in[1];
    const int* dst   = (const int*)d_in[2];
    const float* W1  = (const float*)d_in[3];
    const float* b1  = (const float*)d_in[4];
    const float* W2  = (const float*)d_in[5];
    const float* b2  = (const float*)d_in[6];
    const float* pa  = (const float*)d_in[7];
    float* out = (float*)d_out;

    const int N = in_sizes[0] / D;   // 100000
    const int E = in_sizes[1];       // 1600000

    // ---- workspace layout ----
    char* ws = (char*)d_ws;
    size_t off = 0;
    float* agg   = (float*)(ws + off); off += (size_t)N * D * sizeof(float);
    int* esrc    = (int*)(ws + off);   off += (size_t)E * sizeof(int);
    int* indeg   = (int*)(ws + off);   off += (size_t)N * sizeof(int);
    int* outcnt  = (int*)(ws + off);   off += (size_t)N * sizeof(int);
    int* cursor  = (int*)(ws + off);   off += (size_t)N * sizeof(int);
    int* rowst   = (int*)(ws + off);   off += (size_t)N * sizeof(int);
    float* inv   = (float*)(ws + off); off += (size_t)N * sizeof(float);
    int* bsums   = (int*)(ws + off);   off += 4096;

    const int NB1 = (N + SCAN_TILE - 1) / SCAN_TILE;

    // zero indeg + outcnt (contiguous)
    hipMemsetAsync(indeg, 0, 2 * (size_t)N * sizeof(int), stream);

    k_degrees<<<(E + 255) / 256, 256, 0, stream>>>(src, dst, outcnt, indeg, E);
    k_makeinv<<<(N + 255) / 256, 256, 0, stream>>>(outcnt, inv, cursor, N);
    k_scan1<<<NB1, SCAN_B, 0, stream>>>(indeg, rowst, bsums, N);
    k_scan2<<<1, 64, 0, stream>>>(bsums, NB1);
    k_scan3<<<NB1, SCAN_B, 0, stream>>>(rowst, bsums, N);
    k_fill<<<(E + 255) / 256, 256, 0, stream>>>(src, dst, rowst, cursor, esrc, E);

    // layer 1: agg = segsum(x*inv); out (h1) = prelu(agg@W1 + b1)
    k_spmm<<<N, 128, 0, stream>>>(x, inv, rowst, indeg, esrc, agg, N);
    k_gemm_bias_prelu<<<(N + GM - 1) / GM, 256, 0, stream>>>(agg, W1, b1, pa, out, N);

    // layer 2: agg = segsum(h1*inv); out = prelu(agg@W2 + b2)
    k_spmm<<<N, 128, 0, stream>>>(out, inv, rowst, indeg, esrc, agg, N);
    k_gemm_bias_prelu<<<(N + GM - 1) / GM, 256, 0, stream>>>(agg, W2, b2, pa, out, N);
}